// Round 8
// baseline (269.588 us; speedup 1.0000x reference)
//
#include <hip/hip_runtime.h>
#include <hip/hip_bf16.h>

#define D 128
#define SCAN_BLK 256
#define SCAN_VPT 4
#define SCAN_TILE (SCAN_BLK * SCAN_VPT)   // 1024

typedef __attribute__((ext_vector_type(8))) short short8;   // 8 bf16
typedef __attribute__((ext_vector_type(4))) float f32x4;    // MFMA C/D frag

// ---------------------------------------------------------------------------
// prep_hist: WT transposes -> bf16, bsum = bl+br, degree histogram.
// pos MUST be zeroed by a prior stream op (hipMemsetAsync) — zeroing inside
// this kernel races with the histogram across blocks (R7 crash).
// ---------------------------------------------------------------------------
__global__ __launch_bounds__(256) void prep_hist(
    const float* __restrict__ Wl, const float* __restrict__ Wr,
    const float* __restrict__ bl, const float* __restrict__ br,
    __hip_bfloat16* __restrict__ WTl, __hip_bfloat16* __restrict__ WTr,
    float* __restrict__ bsum, int* __restrict__ pos,
    const int* __restrict__ edst, int n_edges) {
  const int gtid = blockIdx.x * 256 + threadIdx.x;
  const int gsz = gridDim.x * 256;
  for (int i = gtid; i < D * D; i += gsz) {
    const int k = i >> 7, n = i & 127;       // coalesced reads of row k
    WTl[n * D + k] = __float2bfloat16(Wl[k * D + n]);
    WTr[n * D + k] = __float2bfloat16(Wr[k * D + n]);
  }
  if (gtid < D) bsum[gtid] = bl[gtid] + br[gtid];
  for (int e = gtid; e < n_edges; e += gsz) atomicAdd(&pos[edst[e]], 1);
}

// ---------------------------------------------------------------------------
// scan1: per-tile exclusive scan of deg -> offsets + per-block totals.
// ---------------------------------------------------------------------------
__global__ __launch_bounds__(SCAN_BLK) void scan1_kernel(
    const int* __restrict__ deg, int* __restrict__ offsets,
    int* __restrict__ partials, int n) {
  __shared__ int sdata[SCAN_BLK];
  const int t = threadIdx.x;
  const int base = blockIdx.x * SCAN_TILE + t * SCAN_VPT;

  int v[SCAN_VPT];
  int s = 0;
#pragma unroll
  for (int j = 0; j < SCAN_VPT; ++j) {
    v[j] = (base + j < n) ? deg[base + j] : 0;
    s += v[j];
  }
  sdata[t] = s;
  __syncthreads();
  for (int off = 1; off < SCAN_BLK; off <<= 1) {
    int xv = (t >= off) ? sdata[t - off] : 0;
    __syncthreads();
    sdata[t] += xv;
    __syncthreads();
  }
  int excl = sdata[t] - s;
  if (t == SCAN_BLK - 1) partials[blockIdx.x] = sdata[t];
  int run = excl;
#pragma unroll
  for (int j = 0; j < SCAN_VPT; ++j) {
    if (base + j < n) offsets[base + j] = run;
    run += v[j];
  }
}

// ---------------------------------------------------------------------------
// scan3: add inter-tile prefix (wave 0 sums partials), build pos cursors.
// ---------------------------------------------------------------------------
__global__ __launch_bounds__(SCAN_BLK) void scan3_kernel(
    int* __restrict__ offsets, int* __restrict__ pos,
    const int* __restrict__ partials, int n, int n_edges) {
  __shared__ int s_add;
  const int t = threadIdx.x;
  if (t < 64) {
    int v = 0;
    for (int j = t; j < (int)blockIdx.x; j += 64) v += partials[j];
#pragma unroll
    for (int off = 32; off > 0; off >>= 1) v += __shfl_down(v, off);
    if (t == 0) s_add = v;
  }
  __syncthreads();
  const int add = s_add;
  const int base = blockIdx.x * SCAN_TILE + t * SCAN_VPT;
#pragma unroll
  for (int j = 0; j < SCAN_VPT; ++j) {
    const int i = base + j;
    if (i < n) {
      const int o = offsets[i] + add;
      offsets[i] = o;
      pos[i] = o;
    }
  }
  if (blockIdx.x == 0 && t == 0) offsets[n] = n_edges;
}

// ---------------------------------------------------------------------------
// scatter: pairs[slot] = {src, bits(weight)} in dst-sorted order.
// ---------------------------------------------------------------------------
__global__ __launch_bounds__(256) void scatter_kernel(
    const int* __restrict__ esrc, const int* __restrict__ edst,
    const float* __restrict__ ew, int* __restrict__ pos,
    int2* __restrict__ pairs, int n_edges) {
  const int e = blockIdx.x * 256 + threadIdx.x;
  if (e >= n_edges) return;
  const int d = edst[e];
  const int slot = atomicAdd(&pos[d], 1);
  pairs[slot] = make_int2(esrc[e], __float_as_int(ew[e]));
}

// ---------------------------------------------------------------------------
// spmm: agg[node] = bf16( sum_e w_e * x[src_e] )  — exact fp32 accumulate of
// fp32 x gathers. One wave per node, 4 nodes/block, 4-edge pipelining.
// ---------------------------------------------------------------------------
__global__ __launch_bounds__(256) void spmm(
    const float* __restrict__ x, const int* __restrict__ offsets,
    const int2* __restrict__ pairs, __hip_bfloat16* __restrict__ agg,
    int n_nodes) {
  const int node = blockIdx.x * 4 + (threadIdx.x >> 6);
  if (node >= n_nodes) return;
  const int t = threadIdx.x & 63;     // owns features 2t, 2t+1
  const int begin = offsets[node];
  const int end = offsets[node + 1];

  float2 a = make_float2(0.f, 0.f);
  int i = begin;
  for (; i + 4 <= end; i += 4) {
    const int2 p0 = pairs[i + 0];
    const int2 p1 = pairs[i + 1];
    const int2 p2 = pairs[i + 2];
    const int2 p3 = pairs[i + 3];
    const float2 v0 = *(const float2*)&x[(size_t)p0.x * D + 2 * t];
    const float2 v1 = *(const float2*)&x[(size_t)p1.x * D + 2 * t];
    const float2 v2 = *(const float2*)&x[(size_t)p2.x * D + 2 * t];
    const float2 v3 = *(const float2*)&x[(size_t)p3.x * D + 2 * t];
    const float w0 = __int_as_float(p0.y), w1 = __int_as_float(p1.y);
    const float w2 = __int_as_float(p2.y), w3 = __int_as_float(p3.y);
    a.x = fmaf(w0, v0.x, a.x); a.y = fmaf(w0, v0.y, a.y);
    a.x = fmaf(w1, v1.x, a.x); a.y = fmaf(w1, v1.y, a.y);
    a.x = fmaf(w2, v2.x, a.x); a.y = fmaf(w2, v2.y, a.y);
    a.x = fmaf(w3, v3.x, a.x); a.y = fmaf(w3, v3.y, a.y);
  }
  for (; i < end; ++i) {
    const int2 p = pairs[i];
    const float2 v = *(const float2*)&x[(size_t)p.x * D + 2 * t];
    const float w = __int_as_float(p.y);
    a.x = fmaf(w, v.x, a.x); a.y = fmaf(w, v.y, a.y);
  }
  __hip_bfloat162 o;
  o.x = __float2bfloat16(a.x);
  o.y = __float2bfloat16(a.y);
  *(__hip_bfloat162*)&agg[(size_t)node * D + 2 * t] = o;
}

// ---------------------------------------------------------------------------
// gemm_out: out = agg @ Wl + x @ Wr + bsum. Fused dual-K MFMA GEMM per
// 16-row tile; both operand tiles staged in LDS; out written once.
// ---------------------------------------------------------------------------
__global__ __launch_bounds__(256) void gemm_out(
    const float* __restrict__ x, const __hip_bfloat16* __restrict__ agg,
    const __hip_bfloat16* __restrict__ WTl, const __hip_bfloat16* __restrict__ WTr,
    const float* __restrict__ bsum, float* __restrict__ out) {
  __shared__ __hip_bfloat16 xs[16][136];   // x tile (bf16), +8 pad
  __shared__ __hip_bfloat16 as[16][136];   // agg tile, +8 pad
  const int t = threadIdx.x;
  const int wave = t >> 6;
  const int lane = t & 63;
  const int m = lane & 15;
  const int q = lane >> 4;
  const int rowbase = blockIdx.x * 16;

  short8 bx[2][4], ba[2][4];
#pragma unroll
  for (int c = 0; c < 2; ++c) {
    const int n0 = wave * 32 + c * 16;
#pragma unroll
    for (int ks = 0; ks < 4; ++ks) {
      bx[c][ks] = *(const short8*)&WTr[(n0 + m) * D + ks * 32 + q * 8];
      ba[c][ks] = *(const short8*)&WTl[(n0 + m) * D + ks * 32 + q * 8];
    }
  }

  {
    const int srow = t >> 4;
    const int scol = (t & 15) * 8;
    const float4* src = (const float4*)&x[(size_t)(rowbase + srow) * D + scol];
    const float4 v0 = src[0], v1 = src[1];
    __hip_bfloat16* dst = &xs[srow][scol];
    dst[0] = __float2bfloat16(v0.x); dst[1] = __float2bfloat16(v0.y);
    dst[2] = __float2bfloat16(v0.z); dst[3] = __float2bfloat16(v0.w);
    dst[4] = __float2bfloat16(v1.x); dst[5] = __float2bfloat16(v1.y);
    dst[6] = __float2bfloat16(v1.z); dst[7] = __float2bfloat16(v1.w);
    *(float4*)&as[srow][scol] = *(const float4*)&agg[(size_t)(rowbase + srow) * D + scol];
  }
  __syncthreads();

  f32x4 acc[2];
#pragma unroll
  for (int c = 0; c < 2; ++c)
#pragma unroll
    for (int r = 0; r < 4; ++r) acc[c][r] = 0.f;

#pragma unroll
  for (int ks = 0; ks < 4; ++ks) {
    const short8 afx = *(const short8*)&xs[m][ks * 32 + q * 8];
    const short8 afa = *(const short8*)&as[m][ks * 32 + q * 8];
#pragma unroll
    for (int c = 0; c < 2; ++c) {
      acc[c] = __builtin_amdgcn_mfma_f32_16x16x32_bf16(afx, bx[c][ks], acc[c], 0, 0, 0);
      acc[c] = __builtin_amdgcn_mfma_f32_16x16x32_bf16(afa, ba[c][ks], acc[c], 0, 0, 0);
    }
  }

#pragma unroll
  for (int c = 0; c < 2; ++c) {
    const int n = wave * 32 + c * 16 + m;
    const float b = bsum[n];
#pragma unroll
    for (int r = 0; r < 4; ++r)
      out[(size_t)(rowbase + q * 4 + r) * D + n] = acc[c][r] + b;
  }
}

// ---------------------------------------------------------------------------
extern "C" void kernel_launch(void* const* d_in, const int* in_sizes, int n_in,
                              void* d_out, int out_size, void* d_ws, size_t ws_size,
                              hipStream_t stream) {
  const float* x   = (const float*)d_in[0];
  const int* esrc  = (const int*)d_in[1];
  const int* edst  = (const int*)d_in[2];
  const float* ew  = (const float*)d_in[3];
  const float* Wl  = (const float*)d_in[4];
  const float* bl  = (const float*)d_in[5];
  const float* Wr  = (const float*)d_in[6];
  const float* br  = (const float*)d_in[7];
  float* out = (float*)d_out;

  const int n_nodes = in_sizes[0] / D;   // 100000
  const int n_edges = in_sizes[1];       // 600000

  // Workspace layout (16B aligned sections), total ~31.3 MB
  char* ws = (char*)d_ws;
  size_t off = 0;
  __hip_bfloat16* agg = (__hip_bfloat16*)(ws + off);    // 25.6 MB
  off += (size_t)n_nodes * D * sizeof(__hip_bfloat16);
  off = (off + 15) & ~15ull;
  int* offsets = (int*)(ws + off);
  off += (size_t)(n_nodes + 1) * sizeof(int);
  off = (off + 15) & ~15ull;
  int* pos = (int*)(ws + off);                          // degree, then cursors
  off += (size_t)n_nodes * sizeof(int);
  off = (off + 15) & ~15ull;
  int* partials = (int*)(ws + off);
  off += 1024 * sizeof(int);
  off = (off + 15) & ~15ull;
  int2* pairs = (int2*)(ws + off);                      // 4.8 MB
  off += (size_t)n_edges * sizeof(int2);
  off = (off + 15) & ~15ull;
  __hip_bfloat16* WTl = (__hip_bfloat16*)(ws + off);
  off += (size_t)D * D * sizeof(__hip_bfloat16);
  __hip_bfloat16* WTr = (__hip_bfloat16*)(ws + off);
  off += (size_t)D * D * sizeof(__hip_bfloat16);
  float* bsum = (float*)(ws + off);
  off += D * sizeof(float);

  const int n_rowtiles = (n_nodes + 15) / 16;           // 6250 (exact)

  // Stream-ordered zero of the degree array BEFORE the histogram dispatch
  // (zero+hist in one kernel is a cross-block race — R7 crash).
  hipMemsetAsync(pos, 0, (size_t)n_nodes * sizeof(int), stream);

  prep_hist<<<1024, 256, 0, stream>>>(Wl, Wr, bl, br, WTl, WTr, bsum, pos,
                                      edst, n_edges);

  const int nparts = (n_nodes + SCAN_TILE - 1) / SCAN_TILE;   // 98
  scan1_kernel<<<nparts, SCAN_BLK, 0, stream>>>(pos, offsets, partials, n_nodes);
  scan3_kernel<<<nparts, SCAN_BLK, 0, stream>>>(offsets, pos, partials, n_nodes, n_edges);

  scatter_kernel<<<(n_edges + 255) / 256, 256, 0, stream>>>(esrc, edst, ew, pos, pairs, n_edges);

  spmm<<<(n_nodes + 3) / 4, 256, 0, stream>>>(x, offsets, pairs, agg, n_nodes);

  gemm_out<<<n_rowtiles, 256, 0, stream>>>(x, agg, WTl, WTr, bsum, out);
}